// Round 8
// baseline (407.541 us; speedup 1.0000x reference)
//
#include <hip/hip_runtime.h>

// ResRGCN: h=x@W1+b1; 2x {per-(dst,rel) mean aggr -> [h|agg]@[root;W_r]+bias, h+=relu}; out=h@W2+b2
// Layer 3 of the reference is dead (output discarded) and is skipped.
// Edges counting-sorted by key = dst*8+type -> per-(node,rel) segments contiguous;
// each wave's 4 nodes own one flat contiguous edge range (33 boundaries).
// k_conv gathers via global_load_lds DMA: one size=16 DMA lands 8 full rows
// (per-lane src = row[lane>>3]*128 + (lane&7)*16, linear LDS dest). 16-edge
// chunks, 2 DMAs each, per-wave double-buffered slots, counted vmcnt(2) waits
// (sched_barrier per rule 18). No dest VGPRs -> no spill hazard (r7 lesson).

#define HDIM 64
#define RREL 8
#define KCAT 576   // 64 (root/self) + 8*64 (relations)
#define NPB  16    // nodes per workgroup in MFMA kernels
#define APAD 584   // padded LDS row
#define CH   16    // edges per chunk (2 DMAs x 8 rows)

typedef short  short8 __attribute__((ext_vector_type(8)));
typedef __bf16 bf16x8 __attribute__((ext_vector_type(8)));
typedef float  f32x4  __attribute__((ext_vector_type(4)));
typedef unsigned int uint;
typedef unsigned short ushort;

#define GLB(p) ((const __attribute__((address_space(1))) void*)(p))
#define LDS(p) ((__attribute__((address_space(3))) void*)(p))

static __device__ __forceinline__ ushort f2bf(float f) {
  uint u = __builtin_bit_cast(uint, f);
  u += 0x7FFFu + ((u >> 16) & 1u);
  return (ushort)(u >> 16);
}
static __device__ __forceinline__ float bf2f(ushort s) {
  uint u = ((uint)s) << 16;
  return __builtin_bit_cast(float, u);
}

// ---- weight prep: wt_lin1[j][k]=lin1_w[k][j]; wt_conv[l][j][k] = cat(root_l, W_r)^T in bf16
__global__ void k_prep_wt(const float* __restrict__ lin1_w, const float* __restrict__ bases,
                          const float* __restrict__ comp, const float* __restrict__ root,
                          ushort* __restrict__ wt_lin1, ushort* __restrict__ wt_conv) {
  int t = blockIdx.x * 256 + threadIdx.x;
  if (t < HDIM * HDIM) {
    int j = t >> 6, k = t & 63;
    wt_lin1[t] = f2bf(lin1_w[k * HDIM + j]);
  }
  if (t < 2 * HDIM * KCAT) {
    int l = t / (HDIM * KCAT);
    int rem = t - l * (HDIM * KCAT);
    int j = rem / KCAT;
    int k = rem - j * KCAT;
    float v;
    if (k < HDIM) {
      v = root[(l * HDIM + k) * HDIM + j];
    } else {
      int r = (k - HDIM) >> 6;
      int i = (k - HDIM) & 63;
      v = 0.f;
      #pragma unroll
      for (int b = 0; b < 4; ++b)
        v += comp[(l * RREL + r) * 4 + b] * bases[((l * 4 + b) * HDIM + i) * HDIM + j];
    }
    wt_conv[t] = f2bf(v);
  }
}

// ---- build CSR over keys = dst*8 + type (M = 8N bins)
__global__ void k_hist(const int* __restrict__ dst, const int* __restrict__ et, int E,
                       uint* __restrict__ deg) {
  int e = blockIdx.x * 256 + threadIdx.x;
  if (e < E) atomicAdd(&deg[dst[e] * RREL + et[e]], 1u);
}

__global__ void k_scan1(const uint* __restrict__ deg, uint* __restrict__ off,
                        uint* __restrict__ bsum, int M) {
  __shared__ uint s[256];
  int t = threadIdx.x;
  int base = blockIdx.x * 1024 + t * 4;
  uint v0 = 0, v1 = 0, v2 = 0, v3 = 0;
  if (base + 3 < M) {
    uint4 u = *(const uint4*)(deg + base);
    v0 = u.x; v1 = u.y; v2 = u.z; v3 = u.w;
  } else {
    if (base < M)     v0 = deg[base];
    if (base + 1 < M) v1 = deg[base + 1];
    if (base + 2 < M) v2 = deg[base + 2];
    if (base + 3 < M) v3 = deg[base + 3];
  }
  uint tsum = v0 + v1 + v2 + v3;
  s[t] = tsum;
  __syncthreads();
  for (int o = 1; o < 256; o <<= 1) {
    uint u = (t >= o) ? s[t - o] : 0u;
    __syncthreads();
    s[t] += u;
    __syncthreads();
  }
  uint ex = s[t] - tsum;
  if (base < M)     off[base]     = ex;
  if (base + 1 < M) off[base + 1] = ex + v0;
  if (base + 2 < M) off[base + 2] = ex + v0 + v1;
  if (base + 3 < M) off[base + 3] = ex + v0 + v1 + v2;
  if (t == 255) bsum[blockIdx.x] = s[255];
}

__global__ void k_scan2(uint* __restrict__ bsum, uint* __restrict__ off, int nblk, int M, uint E) {
  __shared__ uint s[1024];
  int t = threadIdx.x;
  uint v = (t < nblk) ? bsum[t] : 0u;
  s[t] = v;
  __syncthreads();
  for (int o = 1; o < 1024; o <<= 1) {
    uint u = (t >= o) ? s[t - o] : 0u;
    __syncthreads();
    s[t] += u;
    __syncthreads();
  }
  if (t < nblk) bsum[t] = s[t] - v;
  if (t == 0) off[M] = E;
}

__global__ void k_scan3(uint* __restrict__ off, const uint* __restrict__ bsum, int M) {
  int i = blockIdx.x * 256 + threadIdx.x;
  if (i < M) off[i] += bsum[i >> 10];
}

// counting-sort scatter; atomicSub on deg leaves it zeroed (self-restoring)
__global__ void k_scatter(const int* __restrict__ src, const int* __restrict__ dst,
                          const int* __restrict__ et, int E, const uint* __restrict__ off,
                          uint* __restrict__ deg, uint* __restrict__ sorted) {
  int e = blockIdx.x * 256 + threadIdx.x;
  if (e < E) {
    int key = dst[e] * RREL + et[e];
    uint p = off[key] + atomicSub(&deg[key], 1u) - 1u;
    sorted[p] = (uint)src[e];
  }
}

// ---- lin1: hb = bf16(x @ W1 + b1) (MFMA over K=64)
__global__ void k_lin1(const float* __restrict__ x, const ushort* __restrict__ wt,
                       const float* __restrict__ bias, ushort* __restrict__ hb, int N) {
  __shared__ ushort A[NPB][72];
  int nodebase = blockIdx.x * NPB;
  for (int i = threadIdx.x; i < NPB * HDIM; i += 256) {
    int nl = i >> 6, c = i & 63;
    int n = nodebase + nl;
    A[nl][c] = (n < N) ? f2bf(x[(size_t)n * HDIM + c]) : (ushort)0;
  }
  __syncthreads();
  int lane = threadIdx.x & 63, wid = threadIdx.x >> 6;
  int m16 = lane & 15, khi = lane >> 4;
  int colbase = wid * 16;
  f32x4 acc = {0.f, 0.f, 0.f, 0.f};
  #pragma unroll
  for (int kk = 0; kk < HDIM; kk += 32) {
    int k0 = kk + khi * 8;
    short8 av = *(const short8*)&A[m16][k0];
    short8 bv = *(const short8*)&wt[(colbase + m16) * HDIM + k0];
    acc = __builtin_amdgcn_mfma_f32_16x16x32_bf16(
        __builtin_bit_cast(bf16x8, av), __builtin_bit_cast(bf16x8, bv), acc, 0, 0, 0);
  }
  int j = colbase + m16;
  float bj = bias[j];
  #pragma unroll
  for (int r = 0; r < 4; ++r) {
    int nl = khi * 4 + r;
    int n = nodebase + nl;
    if (n < N) hb[(size_t)n * HDIM + j] = f2bf(acc[r] + bj);
  }
}

// ---- fused RGCN layer: LDS-DMA gather pipeline + scalar boundary-flush walk
__global__ void __launch_bounds__(256, 4)
k_conv(const uint* __restrict__ off8, const uint* __restrict__ sorted,
       const ushort* __restrict__ hb_in, const ushort* __restrict__ wt,
       const float* __restrict__ bias, ushort* __restrict__ hb_out, int N) {
  __shared__ ushort A[NPB][APAD];                 // 18.7 KB
  __shared__ __align__(16) ushort land[4][2][CH * HDIM];  // 4 waves x 2 slots x 2KB = 16 KB
  int nb0 = blockIdx.x * NPB;
  int lane = threadIdx.x & 63, wid = threadIdx.x >> 6;

  // stage self rows: thread t -> row t>>4, chans (t&15)*4 (one uint2 each)
  {
    int tt = threadIdx.x;
    int nl = tt >> 4, c = (tt & 15) * 4;
    int n = nb0 + nl;
    uint2 v = {0u, 0u};
    if (n < N) v = *(const uint2*)&hb_in[(size_t)n * HDIM + c];
    *(uint2*)&A[nl][c] = v;
  }

  // this wave's 4 nodes: 33 boundaries in lanes 0..32
  int n0 = nb0 + wid * 4;
  uint M8 = (uint)N * RREL;
  uint bidx = (uint)n0 * RREL + (uint)lane;
  uint bl = (bidx > M8) ? M8 : bidx;              // clamp -> empty segs past N
  uint bvv = (lane < 33) ? off8[bl] : 0u;

  uint e0   = (uint)__builtin_amdgcn_readlane((int)bvv, 0);
  uint eEnd = (uint)__builtin_amdgcn_readlane((int)bvv, 32);
  uint nch  = (eEnd - e0 + (CH - 1)) / CH;        // scalar chunk count

  float run = 0.f;
  int ri = 0;
  uint prevb = e0;
  uint nextb = (uint)__builtin_amdgcn_readlane((int)bvv, 1);

  int r8 = lane >> 3;                              // row within DMA octet
  int c8 = lane & 7;                               // 16B column within row
  // stage(c, s): load 16 indices, issue 2 DMAs (8 rows each) into slot s
  auto stage = [&](uint c, uint s) {
    uint p = e0 + c * CH + (uint)r8;
    uint iA = sorted[p] & 0x1FFFFu;                // may overrun; slack covers
    uint iB = sorted[p + 8] & 0x1FFFFu;
    const ushort* sA = hb_in + ((size_t)iA << 6) + ((uint)c8 << 3);
    const ushort* sB = hb_in + ((size_t)iB << 6) + ((uint)c8 << 3);
    __builtin_amdgcn_global_load_lds(GLB(sA), LDS(&land[wid][s][0]), 16, 0, 0);
    __builtin_amdgcn_global_load_lds(GLB(sB), LDS(&land[wid][s][CH * HDIM / 2]), 16, 0, 0);
  };

  if (nch > 0) stage(0, 0);
  for (uint t = 0; t < nch; ++t) {
    uint s = t & 1;
    if (t + 1 < nch) {
      stage(t + 1, s ^ 1);
      __builtin_amdgcn_sched_barrier(0);
      asm volatile("s_waitcnt vmcnt(2)" ::: "memory");   // chunk t landed
      __builtin_amdgcn_sched_barrier(0);
    } else {
      __builtin_amdgcn_sched_barrier(0);
      asm volatile("s_waitcnt vmcnt(0)" ::: "memory");
      __builtin_amdgcn_sched_barrier(0);
    }
    // consume chunk t from slot s: 16 ds_read_u16 (imm offsets) + flush walk
    uint base = e0 + t * CH;
    uint m = eEnd - base;                           // scalar
    if (m > CH) m = CH;
    const ushort* lb = &land[wid][s][lane];
    #pragma unroll
    for (int j = 0; j < CH; ++j) {
      if ((uint)j < m) {                            // scalar guard
        uint pos = base + (uint)j;
        while (pos >= nextb) {                      // scalar flush walk
          float mean = run * __builtin_amdgcn_rcpf(fmaxf((float)(nextb - prevb), 1.0f));
          int row = (wid << 2) + (ri >> 3);
          A[row][HDIM + (ri & 7) * HDIM + lane] = f2bf(mean);
          run = 0.f;
          ++ri;
          prevb = nextb;
          nextb = (uint)__builtin_amdgcn_readlane((int)bvv, ri + 1);
        }
        run += bf2f(lb[j * HDIM]);
      }
    }
  }
  while (ri < 32) {                                 // trailing flushes (incl. empty)
    float mean = run * __builtin_amdgcn_rcpf(fmaxf((float)(nextb - prevb), 1.0f));
    int row = (wid << 2) + (ri >> 3);
    A[row][HDIM + (ri & 7) * HDIM + lane] = f2bf(mean);
    run = 0.f;
    ++ri;
    prevb = nextb;
    if (ri < 32) nextb = (uint)__builtin_amdgcn_readlane((int)bvv, ri + 1);
  }
  __syncthreads();

  // MFMA: [16 x 576] @ [576 x 64]
  int m16 = lane & 15, khi = lane >> 4;
  int colbase = wid * 16;
  f32x4 acc = {0.f, 0.f, 0.f, 0.f};
  #pragma unroll
  for (int kk = 0; kk < KCAT; kk += 32) {
    int k0 = kk + khi * 8;
    short8 av = *(const short8*)&A[m16][k0];
    short8 bv = *(const short8*)&wt[(uint)(colbase + m16) * KCAT + k0];
    acc = __builtin_amdgcn_mfma_f32_16x16x32_bf16(
        __builtin_bit_cast(bf16x8, av), __builtin_bit_cast(bf16x8, bv), acc, 0, 0, 0);
  }
  int j = colbase + m16;
  float bj = bias[j];
  #pragma unroll
  for (int r = 0; r < 4; ++r) {
    int nl = khi * 4 + r;
    int n = nb0 + nl;
    if (n < N) {
      float hs = bf2f(A[nl][j]);                    // self row (residual base)
      float hn = hs + fmaxf(acc[r] + bj, 0.f);
      hb_out[(uint)n * HDIM + j] = f2bf(hn);
    }
  }
}

// ---- lin2: out = h @ W2 + b2  (OUT=2), bf16 input rows via short8 loads
__global__ void k_lin2(const ushort* __restrict__ hb, const float* __restrict__ w,
                       const float* __restrict__ b, float* __restrict__ out, int N) {
  int n = blockIdx.x * 256 + threadIdx.x;
  if (n >= N) return;
  const short8* hr = (const short8*)(hb + (size_t)n * HDIM);
  float a0 = b[0], a1 = b[1];
  #pragma unroll
  for (int i = 0; i < 8; ++i) {
    short8 hv8 = hr[i];
    #pragma unroll
    for (int k = 0; k < 8; ++k) {
      float hv = bf2f((ushort)hv8[k]);
      a0 += hv * w[2 * (i * 8 + k)];
      a1 += hv * w[2 * (i * 8 + k) + 1];
    }
  }
  out[2 * n] = a0;
  out[2 * n + 1] = a1;
}

extern "C" void kernel_launch(void* const* d_in, const int* in_sizes, int n_in,
                              void* d_out, int out_size, void* d_ws, size_t ws_size,
                              hipStream_t stream) {
  const float* x      = (const float*)d_in[0];
  const int*   ei     = (const int*)d_in[1];
  const int*   et     = (const int*)d_in[2];
  const float* lin1_w = (const float*)d_in[3];
  const float* lin1_b = (const float*)d_in[4];
  const float* bases  = (const float*)d_in[5];
  const float* comp   = (const float*)d_in[6];
  const float* root   = (const float*)d_in[7];
  const float* cbias  = (const float*)d_in[8];
  const float* lin2_w = (const float*)d_in[9];
  const float* lin2_b = (const float*)d_in[10];
  float* out = (float*)d_out;

  int N = in_sizes[0] / HDIM;
  int E = in_sizes[2];
  int M = N * RREL;
  const int* srcp = ei;
  const int* dstp = ei + E;

  char* p = (char*)d_ws;
  auto carve = [&](size_t bytes) { char* r = p; p += (bytes + 255) & ~(size_t)255; return r; };
  ushort* hb_a    = (ushort*)carve((size_t)N * HDIM * 2);
  ushort* hb_b    = (ushort*)carve((size_t)N * HDIM * 2);
  uint*   sorted  = (uint*)carve((size_t)(E + 64) * 4);   // +64: chunk-overrun slack
  uint*   deg8    = (uint*)carve((size_t)M * 4);
  uint*   off8    = (uint*)carve((size_t)(M + 1) * 4);
  uint*   bsum    = (uint*)carve(4096);
  ushort* wt_lin1 = (ushort*)carve((size_t)HDIM * HDIM * 2);
  ushort* wt_conv = (ushort*)carve((size_t)2 * HDIM * KCAT * 2);
  carve((size_t)8 << 20);  // slack (masked-index DMA reads stay in ws)

  hipMemsetAsync(deg8, 0, (size_t)M * 4, stream);

  int eb    = (E + 255) / 256;
  int nb    = (N + 255) / 256;
  int nwg   = (N + NPB - 1) / NPB;
  int nblk1 = (M + 1023) / 1024;   // <= 1024 (N <= 131072)
  int mb    = (M + 255) / 256;

  k_prep_wt<<<(2 * HDIM * KCAT + 255) / 256, 256, 0, stream>>>(lin1_w, bases, comp, root, wt_lin1, wt_conv);
  k_hist<<<eb, 256, 0, stream>>>(dstp, et, E, deg8);
  k_scan1<<<nblk1, 256, 0, stream>>>(deg8, off8, bsum, M);
  k_scan2<<<1, 1024, 0, stream>>>(bsum, off8, nblk1, M, (uint)E);
  k_scan3<<<mb, 256, 0, stream>>>(off8, bsum, M);
  k_scatter<<<eb, 256, 0, stream>>>(srcp, dstp, et, E, off8, deg8, sorted);

  k_lin1<<<nwg, 256, 0, stream>>>(x, wt_lin1, lin1_b, hb_a, N);
  k_conv<<<nwg, 256, 0, stream>>>(off8, sorted, hb_a, wt_conv, cbias, hb_b, N);
  k_conv<<<nwg, 256, 0, stream>>>(off8, sorted, hb_b, wt_conv + HDIM * KCAT, cbias + HDIM, hb_a, N);
  k_lin2<<<nb, 256, 0, stream>>>(hb_a, lin2_w, lin2_b, out, N);
}

// Round 9
// 381.307 us; speedup vs baseline: 1.0688x; 1.0688x over previous
//
#include <hip/hip_runtime.h>

// ResRGCN: h=x@W1+b1; 2x {per-(dst,rel) mean aggr -> [h|agg]@[root;W_r]+bias, h+=relu}; out=h@W2+b2
// Layer 3 of the reference is dead (output discarded) and is skipped.
// Edges counting-sorted by key = dst*8+type; each wave's 4 nodes own one flat
// contiguous edge range (33 boundaries). r8 post-mortem: per-chunk index-load ->
// DMA-address dependency serialized the pipeline. Now ALL (<=128) wave edge
// indices are preloaded into 2 VGPRs (2 coalesced loads, one wait); stage() gets
// addresses via register __shfl, so the 2-slot global_load_lds double-buffer
// stays full: {vmcnt(2) -> ds_read x16 -> lgkmcnt(0) -> stage(t+2) -> flush-walk}.
// >128-edge waves (P~1e-10) take a correct serial fallback.

#define HDIM 64
#define RREL 8
#define KCAT 576   // 64 (root/self) + 8*64 (relations)
#define NPB  16    // nodes per workgroup in MFMA kernels
#define APAD 584   // padded LDS row
#define CH   16    // edges per batch (2 DMAs x 8 rows)

typedef short  short8 __attribute__((ext_vector_type(8)));
typedef __bf16 bf16x8 __attribute__((ext_vector_type(8)));
typedef float  f32x4  __attribute__((ext_vector_type(4)));
typedef unsigned int uint;
typedef unsigned short ushort;

#define GLB(p) ((const __attribute__((address_space(1))) void*)(p))
#define LDS(p) ((__attribute__((address_space(3))) void*)(p))

static __device__ __forceinline__ ushort f2bf(float f) {
  uint u = __builtin_bit_cast(uint, f);
  u += 0x7FFFu + ((u >> 16) & 1u);
  return (ushort)(u >> 16);
}
static __device__ __forceinline__ float bf2f(ushort s) {
  uint u = ((uint)s) << 16;
  return __builtin_bit_cast(float, u);
}

// ---- weight prep: wt_lin1[j][k]=lin1_w[k][j]; wt_conv[l][j][k] = cat(root_l, W_r)^T in bf16
__global__ void k_prep_wt(const float* __restrict__ lin1_w, const float* __restrict__ bases,
                          const float* __restrict__ comp, const float* __restrict__ root,
                          ushort* __restrict__ wt_lin1, ushort* __restrict__ wt_conv) {
  int t = blockIdx.x * 256 + threadIdx.x;
  if (t < HDIM * HDIM) {
    int j = t >> 6, k = t & 63;
    wt_lin1[t] = f2bf(lin1_w[k * HDIM + j]);
  }
  if (t < 2 * HDIM * KCAT) {
    int l = t / (HDIM * KCAT);
    int rem = t - l * (HDIM * KCAT);
    int j = rem / KCAT;
    int k = rem - j * KCAT;
    float v;
    if (k < HDIM) {
      v = root[(l * HDIM + k) * HDIM + j];
    } else {
      int r = (k - HDIM) >> 6;
      int i = (k - HDIM) & 63;
      v = 0.f;
      #pragma unroll
      for (int b = 0; b < 4; ++b)
        v += comp[(l * RREL + r) * 4 + b] * bases[((l * 4 + b) * HDIM + i) * HDIM + j];
    }
    wt_conv[t] = f2bf(v);
  }
}

// ---- build CSR over keys = dst*8 + type (M = 8N bins)
__global__ void k_hist(const int* __restrict__ dst, const int* __restrict__ et, int E,
                       uint* __restrict__ deg) {
  int e = blockIdx.x * 256 + threadIdx.x;
  if (e < E) atomicAdd(&deg[dst[e] * RREL + et[e]], 1u);
}

__global__ void k_scan1(const uint* __restrict__ deg, uint* __restrict__ off,
                        uint* __restrict__ bsum, int M) {
  __shared__ uint s[256];
  int t = threadIdx.x;
  int base = blockIdx.x * 1024 + t * 4;
  uint v0 = 0, v1 = 0, v2 = 0, v3 = 0;
  if (base + 3 < M) {
    uint4 u = *(const uint4*)(deg + base);
    v0 = u.x; v1 = u.y; v2 = u.z; v3 = u.w;
  } else {
    if (base < M)     v0 = deg[base];
    if (base + 1 < M) v1 = deg[base + 1];
    if (base + 2 < M) v2 = deg[base + 2];
    if (base + 3 < M) v3 = deg[base + 3];
  }
  uint tsum = v0 + v1 + v2 + v3;
  s[t] = tsum;
  __syncthreads();
  for (int o = 1; o < 256; o <<= 1) {
    uint u = (t >= o) ? s[t - o] : 0u;
    __syncthreads();
    s[t] += u;
    __syncthreads();
  }
  uint ex = s[t] - tsum;
  if (base < M)     off[base]     = ex;
  if (base + 1 < M) off[base + 1] = ex + v0;
  if (base + 2 < M) off[base + 2] = ex + v0 + v1;
  if (base + 3 < M) off[base + 3] = ex + v0 + v1 + v2;
  if (t == 255) bsum[blockIdx.x] = s[255];
}

__global__ void k_scan2(uint* __restrict__ bsum, uint* __restrict__ off, int nblk, int M, uint E) {
  __shared__ uint s[1024];
  int t = threadIdx.x;
  uint v = (t < nblk) ? bsum[t] : 0u;
  s[t] = v;
  __syncthreads();
  for (int o = 1; o < 1024; o <<= 1) {
    uint u = (t >= o) ? s[t - o] : 0u;
    __syncthreads();
    s[t] += u;
    __syncthreads();
  }
  if (t < nblk) bsum[t] = s[t] - v;
  if (t == 0) off[M] = E;
}

__global__ void k_scan3(uint* __restrict__ off, const uint* __restrict__ bsum, int M) {
  int i = blockIdx.x * 256 + threadIdx.x;
  if (i < M) off[i] += bsum[i >> 10];
}

// counting-sort scatter; atomicSub on deg leaves it zeroed (self-restoring)
__global__ void k_scatter(const int* __restrict__ src, const int* __restrict__ dst,
                          const int* __restrict__ et, int E, const uint* __restrict__ off,
                          uint* __restrict__ deg, uint* __restrict__ sorted) {
  int e = blockIdx.x * 256 + threadIdx.x;
  if (e < E) {
    int key = dst[e] * RREL + et[e];
    uint p = off[key] + atomicSub(&deg[key], 1u) - 1u;
    sorted[p] = (uint)src[e];
  }
}

// ---- lin1: hb = bf16(x @ W1 + b1) (MFMA over K=64)
__global__ void k_lin1(const float* __restrict__ x, const ushort* __restrict__ wt,
                       const float* __restrict__ bias, ushort* __restrict__ hb, int N) {
  __shared__ ushort A[NPB][72];
  int nodebase = blockIdx.x * NPB;
  for (int i = threadIdx.x; i < NPB * HDIM; i += 256) {
    int nl = i >> 6, c = i & 63;
    int n = nodebase + nl;
    A[nl][c] = (n < N) ? f2bf(x[(size_t)n * HDIM + c]) : (ushort)0;
  }
  __syncthreads();
  int lane = threadIdx.x & 63, wid = threadIdx.x >> 6;
  int m16 = lane & 15, khi = lane >> 4;
  int colbase = wid * 16;
  f32x4 acc = {0.f, 0.f, 0.f, 0.f};
  #pragma unroll
  for (int kk = 0; kk < HDIM; kk += 32) {
    int k0 = kk + khi * 8;
    short8 av = *(const short8*)&A[m16][k0];
    short8 bv = *(const short8*)&wt[(colbase + m16) * HDIM + k0];
    acc = __builtin_amdgcn_mfma_f32_16x16x32_bf16(
        __builtin_bit_cast(bf16x8, av), __builtin_bit_cast(bf16x8, bv), acc, 0, 0, 0);
  }
  int j = colbase + m16;
  float bj = bias[j];
  #pragma unroll
  for (int r = 0; r < 4; ++r) {
    int nl = khi * 4 + r;
    int n = nodebase + nl;
    if (n < N) hb[(size_t)n * HDIM + j] = f2bf(acc[r] + bj);
  }
}

// ---- fused RGCN layer: reg-resident indices + full DMA double-buffer + flush walk
__global__ void __launch_bounds__(256, 4)
k_conv(const uint* __restrict__ off8, const uint* __restrict__ sorted,
       const ushort* __restrict__ hb_in, const ushort* __restrict__ wt,
       const float* __restrict__ bias, ushort* __restrict__ hb_out, int N) {
  __shared__ ushort A[NPB][APAD];                          // 18.7 KB
  __shared__ __align__(16) ushort land[4][2][CH * HDIM];   // 16 KB
  int nb0 = blockIdx.x * NPB;
  int lane = threadIdx.x & 63, wid = threadIdx.x >> 6;

  // stage self rows: thread t -> row t>>4, chans (t&15)*4 (one uint2 each)
  {
    int tt = threadIdx.x;
    int nl = tt >> 4, c = (tt & 15) * 4;
    int n = nb0 + nl;
    uint2 v = {0u, 0u};
    if (n < N) v = *(const uint2*)&hb_in[(size_t)n * HDIM + c];
    *(uint2*)&A[nl][c] = v;
  }

  // this wave's 4 nodes: 33 boundaries in lanes 0..32
  int n0 = nb0 + wid * 4;
  uint M8 = (uint)N * RREL;
  uint bidx = (uint)n0 * RREL + (uint)lane;
  uint bl = (bidx > M8) ? M8 : bidx;               // clamp -> empty segs past N
  uint bvv = (lane < 33) ? off8[bl] : 0u;

  uint e0   = (uint)__builtin_amdgcn_readlane((int)bvv, 0);
  uint eEnd = (uint)__builtin_amdgcn_readlane((int)bvv, 32);
  uint tot  = eEnd - e0;
  uint nbat = (tot + CH - 1) / CH;
  uint cap8 = nbat > 8u ? 8u : nbat;               // <=128 edges pipelined

  // preload up to 128 edge indices into 2 regs (2 coalesced loads; slack covers overrun)
  uint iv0 = sorted[e0 + (uint)lane];
  uint iv1 = sorted[e0 + 64u + (uint)lane];

  float run = 0.f;
  int ri = 0;
  uint prevb = e0;
  uint nextb = (uint)__builtin_amdgcn_readlane((int)bvv, 1);
  const ushort* hlane = hb_in + lane;

  int r8i = lane >> 3, c8 = lane & 7;
  auto stage = [&](uint t, uint s) {               // addresses from regs -- no VMEM dep
    int sb = (int)((t & 3u) * CH);
    int srcv = (int)((t < 4u) ? iv0 : iv1);
    uint iA = (uint)__shfl(srcv, sb + r8i) & 0x1FFFFu;
    uint iB = (uint)__shfl(srcv, sb + 8 + r8i) & 0x1FFFFu;
    const ushort* sA = hb_in + ((size_t)iA << 6) + ((uint)c8 << 3);
    const ushort* sB = hb_in + ((size_t)iB << 6) + ((uint)c8 << 3);
    __builtin_amdgcn_global_load_lds(GLB(sA), LDS(&land[wid][s][0]), 16, 0, 0);
    __builtin_amdgcn_global_load_lds(GLB(sB), LDS(&land[wid][s][CH * HDIM / 2]), 16, 0, 0);
  };

  if (cap8 > 0) {
    // drain all prior vmem (self rows, iv, bvv) so counted waits see only our DMAs
    asm volatile("s_waitcnt vmcnt(0)" ::: "memory");
    __builtin_amdgcn_sched_barrier(0);
    stage(0, 0);
    stage(1, 1);
    for (uint t = 0; t < cap8; ++t) {
      uint s = t & 1u;
      if (t + 1u < cap8) {
        asm volatile("s_waitcnt vmcnt(2)" ::: "memory");  // batch t landed
      } else {
        asm volatile("s_waitcnt vmcnt(0)" ::: "memory");  // drain
      }
      __builtin_amdgcn_sched_barrier(0);
      // read all 16 values for this lane's channel
      float g[CH];
      const ushort* lb = &land[wid][s][lane];
      #pragma unroll
      for (int j = 0; j < CH; ++j) g[j] = bf2f(lb[j * HDIM]);
      asm volatile("s_waitcnt lgkmcnt(0)" ::: "memory");  // ds reads done before restage
      __builtin_amdgcn_sched_barrier(0);
      if (t + 2u < cap8) stage(t + 2u, s);                // refill slot early
      // scalar boundary-flush walk
      uint base = e0 + t * CH;
      uint m = eEnd - base;                               // scalar
      if (m > CH) m = CH;
      #pragma unroll
      for (int j = 0; j < CH; ++j) {
        if ((uint)j < m) {                                // scalar guard
          uint pos = base + (uint)j;
          while (pos >= nextb) {                          // scalar flush walk
            float mean = run * __builtin_amdgcn_rcpf(fmaxf((float)(nextb - prevb), 1.0f));
            int row = (wid << 2) + (ri >> 3);
            A[row][HDIM + (ri & 7) * HDIM + lane] = f2bf(mean);
            run = 0.f;
            ++ri;
            prevb = nextb;
            nextb = (uint)__builtin_amdgcn_readlane((int)bvv, ri + 1);
          }
          run += g[j];
        }
      }
    }
  }
  asm volatile("" ::: "memory");                          // keep later loads below the pipeline
  // serial fallback for >128-edge waves (P ~ 1e-10, correctness only)
  for (uint e = e0 + cap8 * (uint)CH; e < eEnd; ++e) {
    uint idx = sorted[e] & 0x1FFFFu;
    float v = bf2f(hlane[(size_t)idx << 6]);
    while (e >= nextb) {
      float mean = run * __builtin_amdgcn_rcpf(fmaxf((float)(nextb - prevb), 1.0f));
      int row = (wid << 2) + (ri >> 3);
      A[row][HDIM + (ri & 7) * HDIM + lane] = f2bf(mean);
      run = 0.f;
      ++ri;
      prevb = nextb;
      nextb = (uint)__builtin_amdgcn_readlane((int)bvv, ri + 1);
    }
    run += v;
  }
  while (ri < 32) {                                       // trailing flushes (incl. empty)
    float mean = run * __builtin_amdgcn_rcpf(fmaxf((float)(nextb - prevb), 1.0f));
    int row = (wid << 2) + (ri >> 3);
    A[row][HDIM + (ri & 7) * HDIM + lane] = f2bf(mean);
    run = 0.f;
    ++ri;
    prevb = nextb;
    if (ri < 32) nextb = (uint)__builtin_amdgcn_readlane((int)bvv, ri + 1);
  }
  __syncthreads();

  // MFMA: [16 x 576] @ [576 x 64]
  int m16 = lane & 15, khi = lane >> 4;
  int colbase = wid * 16;
  f32x4 acc = {0.f, 0.f, 0.f, 0.f};
  #pragma unroll
  for (int kk = 0; kk < KCAT; kk += 32) {
    int k0 = kk + khi * 8;
    short8 av = *(const short8*)&A[m16][k0];
    short8 bv = *(const short8*)&wt[(uint)(colbase + m16) * KCAT + k0];
    acc = __builtin_amdgcn_mfma_f32_16x16x32_bf16(
        __builtin_bit_cast(bf16x8, av), __builtin_bit_cast(bf16x8, bv), acc, 0, 0, 0);
  }
  int j = colbase + m16;
  float bj = bias[j];
  #pragma unroll
  for (int r = 0; r < 4; ++r) {
    int nl = khi * 4 + r;
    int n = nb0 + nl;
    if (n < N) {
      float hs = bf2f(A[nl][j]);                          // self row (residual base)
      float hn = hs + fmaxf(acc[r] + bj, 0.f);
      hb_out[(uint)n * HDIM + j] = f2bf(hn);
    }
  }
}

// ---- lin2: out = h @ W2 + b2  (OUT=2), bf16 input rows via short8 loads
__global__ void k_lin2(const ushort* __restrict__ hb, const float* __restrict__ w,
                       const float* __restrict__ b, float* __restrict__ out, int N) {
  int n = blockIdx.x * 256 + threadIdx.x;
  if (n >= N) return;
  const short8* hr = (const short8*)(hb + (size_t)n * HDIM);
  float a0 = b[0], a1 = b[1];
  #pragma unroll
  for (int i = 0; i < 8; ++i) {
    short8 hv8 = hr[i];
    #pragma unroll
    for (int k = 0; k < 8; ++k) {
      float hv = bf2f((ushort)hv8[k]);
      a0 += hv * w[2 * (i * 8 + k)];
      a1 += hv * w[2 * (i * 8 + k) + 1];
    }
  }
  out[2 * n] = a0;
  out[2 * n + 1] = a1;
}

extern "C" void kernel_launch(void* const* d_in, const int* in_sizes, int n_in,
                              void* d_out, int out_size, void* d_ws, size_t ws_size,
                              hipStream_t stream) {
  const float* x      = (const float*)d_in[0];
  const int*   ei     = (const int*)d_in[1];
  const int*   et     = (const int*)d_in[2];
  const float* lin1_w = (const float*)d_in[3];
  const float* lin1_b = (const float*)d_in[4];
  const float* bases  = (const float*)d_in[5];
  const float* comp   = (const float*)d_in[6];
  const float* root   = (const float*)d_in[7];
  const float* cbias  = (const float*)d_in[8];
  const float* lin2_w = (const float*)d_in[9];
  const float* lin2_b = (const float*)d_in[10];
  float* out = (float*)d_out;

  int N = in_sizes[0] / HDIM;
  int E = in_sizes[2];
  int M = N * RREL;
  const int* srcp = ei;
  const int* dstp = ei + E;

  char* p = (char*)d_ws;
  auto carve = [&](size_t bytes) { char* r = p; p += (bytes + 255) & ~(size_t)255; return r; };
  ushort* hb_a    = (ushort*)carve((size_t)N * HDIM * 2);
  ushort* hb_b    = (ushort*)carve((size_t)N * HDIM * 2);
  uint*   sorted  = (uint*)carve((size_t)(E + 160) * 4);  // +160: iv preload overrun slack
  uint*   deg8    = (uint*)carve((size_t)M * 4);
  uint*   off8    = (uint*)carve((size_t)(M + 1) * 4);
  uint*   bsum    = (uint*)carve(4096);
  ushort* wt_lin1 = (ushort*)carve((size_t)HDIM * HDIM * 2);
  ushort* wt_conv = (ushort*)carve((size_t)2 * HDIM * KCAT * 2);
  carve((size_t)8 << 20);  // slack (masked-index DMA reads stay in ws)

  hipMemsetAsync(deg8, 0, (size_t)M * 4, stream);

  int eb    = (E + 255) / 256;
  int nb    = (N + 255) / 256;
  int nwg   = (N + NPB - 1) / NPB;
  int nblk1 = (M + 1023) / 1024;   // <= 1024 (N <= 131072)
  int mb    = (M + 255) / 256;

  k_prep_wt<<<(2 * HDIM * KCAT + 255) / 256, 256, 0, stream>>>(lin1_w, bases, comp, root, wt_lin1, wt_conv);
  k_hist<<<eb, 256, 0, stream>>>(dstp, et, E, deg8);
  k_scan1<<<nblk1, 256, 0, stream>>>(deg8, off8, bsum, M);
  k_scan2<<<1, 1024, 0, stream>>>(bsum, off8, nblk1, M, (uint)E);
  k_scan3<<<mb, 256, 0, stream>>>(off8, bsum, M);
  k_scatter<<<eb, 256, 0, stream>>>(srcp, dstp, et, E, off8, deg8, sorted);

  k_lin1<<<nwg, 256, 0, stream>>>(x, wt_lin1, lin1_b, hb_a, N);
  k_conv<<<nwg, 256, 0, stream>>>(off8, sorted, hb_a, wt_conv, cbias, hb_b, N);
  k_conv<<<nwg, 256, 0, stream>>>(off8, sorted, hb_b, wt_conv + HDIM * KCAT, cbias + HDIM, hb_a, N);
  k_lin2<<<nb, 256, 0, stream>>>(hb_a, lin2_w, lin2_b, out, N);
}